// Round 10
// baseline (201.112 us; speedup 1.0000x reference)
//
#include <hip/hip_runtime.h>

typedef __bf16 bf16x8 __attribute__((ext_vector_type(8)));
typedef __bf16 bf16x4 __attribute__((ext_vector_type(4)));
typedef float  f32x4  __attribute__((ext_vector_type(4)));

#define BK 64

__device__ __forceinline__ void g2l16(const void* g, void* l) {
    __builtin_amdgcn_global_load_lds((const __attribute__((address_space(1))) void*)g,
                                     (__attribute__((address_space(3))) void*)l, 16, 0, 0);
}

// Staging geometry (all gemms): [rows][BK=64] bf16 tiles in LDS, unpadded,
// 16B-unit XOR swizzle (unit ^= row&7) realized by swizzling the global
// SOURCE column (g2l writes lane-linear; reg-staged writes lane-linear).
// Fragment read XORs back -> 0 bank conflicts (R3-verified).

// ---------------------------------------------------------------------------
// proj: q/k/v = xb @ Wb^T + b. R10: counted-vmcnt 3-buffer pipeline, exactly
// the logits-R9 verified geometry (128x64 tile, 24KB x 3 stages, 6 g2l/stage,
// vmcnt(6), K=256 -> 4 iters, prologue covers 2). proj was the largest
// untouched drain-0 kernel (~37us @ 1.8TB/s for 67MB). Grid (256,4,3).
// Epilogues (z<2 row-major q/k; z==2 transposed vT) reuse stage-0 LDS after
// the final vmcnt(0)+barrier, full-line bf16x8 streaming stores (R1-proven).
__global__ __launch_bounds__(256)
void gemm_proj(const __bf16* __restrict__ A, const __bf16* __restrict__ Wb,
               __bf16* __restrict__ qkv, const float* __restrict__ bpack)
{
    __shared__ __align__(16) __bf16 smem[3 * 12288];   // 73728 B
    // stage s: A at s*24576 B (16KB, 128 rows), B at s*24576+16384 (8KB, 64 rows)

    const int tid  = threadIdx.x;
    const int w    = tid >> 6;
    const int lane = tid & 63;
    const int quad = lane >> 4;
    const int l16  = lane & 15;
    const int wm   = w & 1;        // 64-row half of A-tile
    const int wn   = w >> 1;       // 32-row half of B-tile

    const int m0 = blockIdx.x * 128;
    const int n0 = blockIdx.y * 64;
    const int z  = blockIdx.z;

    const __bf16* Bb   = Wb + (size_t)z * 131072;
    const float*  bias = bpack + z * 256;

    const int srow = (w << 3) + (lane >> 3);           // 0..31
    const int scol = ((lane & 7) ^ (lane >> 3)) << 3;

    const __bf16* Ag = A  + (size_t)(m0 + srow) * 256 + scol;
    const __bf16* Bg = Bb + (size_t)(n0 + srow) * 256 + scol;

    f32x4 acc[4][2] = {};

    auto STAGE = [&](int buf, int k0) {
        char* base = (char*)smem + buf * 24576;
        #pragma unroll
        for (int c = 0; c < 4; c++)
            g2l16(Ag + (size_t)(c * 32) * 256 + k0, base + w * 1024 + c * 4096);
        #pragma unroll
        for (int c = 0; c < 2; c++)
            g2l16(Bg + (size_t)(c * 32) * 256 + k0, base + 16384 + w * 1024 + c * 4096);
    };

    STAGE(0, 0);
    STAGE(1, 64);

    for (int t = 0; t < 4; t++) {
        if (t < 3) asm volatile("s_waitcnt vmcnt(6)" ::: "memory");
        else       asm volatile("s_waitcnt vmcnt(0)" ::: "memory");
        __builtin_amdgcn_sched_barrier(0);
        __builtin_amdgcn_s_barrier();

        if (t < 2) STAGE((t + 2) % 3, (t + 2) * BK);

        const __bf16* As = smem + (t % 3) * 12288;
        const __bf16* Bs = As + 8192;
        #pragma unroll
        for (int kk = 0; kk < BK; kk += 32) {
            const int ub = kk >> 3;
            bf16x8 a[4], b[2];
            #pragma unroll
            for (int mt = 0; mt < 4; mt++) {
                const int row = wm * 64 + mt * 16 + l16;
                const int cp  = ((quad + ub) ^ (row & 7)) << 3;
                a[mt] = *(const bf16x8*)&As[row * BK + cp];
            }
            #pragma unroll
            for (int nt = 0; nt < 2; nt++) {
                const int row = wn * 32 + nt * 16 + l16;
                const int cp  = ((quad + ub) ^ (row & 7)) << 3;
                b[nt] = *(const bf16x8*)&Bs[row * BK + cp];
            }
            #pragma unroll
            for (int mt = 0; mt < 4; mt++)
                #pragma unroll
                for (int nt = 0; nt < 2; nt++)
                    acc[mt][nt] = __builtin_amdgcn_mfma_f32_16x16x32_bf16(
                        a[mt], b[nt], acc[mt][nt], 0, 0, 0);
        }
    }

    // epilogue in stage-0 region (last read by compute t=3, buf 0; fenced).
    __syncthreads();
    if (z < 2) {
        // [128][64] swizzled tile -> row-major q/k, full-line stores
        #pragma unroll
        for (int mt = 0; mt < 4; mt++) {
            const int rl = wm * 64 + mt * 16 + quad * 4;
            #pragma unroll
            for (int nt = 0; nt < 2; nt++) {
                const int cl = wn * 32 + nt * 16 + l16;
                const float bn = bias[n0 + cl];
                #pragma unroll
                for (int r = 0; r < 4; r++) {
                    const int row = rl + r;
                    smem[row * 64 + ((((cl >> 3) ^ (row & 7)) << 3) | (cl & 7))] =
                        (__bf16)(acc[mt][nt][r] + bn);
                }
            }
        }
        __syncthreads();
        __bf16* C = qkv + (size_t)z * 8388608;
        #pragma unroll
        for (int i = 0; i < 4; i++) {
            const int c   = tid + i * 256;       // 1024 bf16x8 chunks
            const int row = c >> 3, u = c & 7;
            *(bf16x8*)&C[(size_t)(m0 + row) * 256 + n0 + u * 8] =
                *(const bf16x8*)&smem[row * 64 + ((u ^ (row & 7)) << 3)];
        }
    } else {
        // vT[b][d][m]: [64][128] transposed swizzled tile, full lines in m
        #pragma unroll
        for (int mt = 0; mt < 4; mt++) {
            const int ml = wm * 64 + mt * 16 + quad * 4;   // multiple of 4
            #pragma unroll
            for (int nt = 0; nt < 2; nt++) {
                const int dl = wn * 32 + nt * 16 + l16;
                const float bn = bias[n0 + dl];
                bf16x4 pk;
                #pragma unroll
                for (int r = 0; r < 4; r++) pk[r] = (__bf16)(acc[mt][nt][r] + bn);
                *(bf16x4*)&smem[dl * 128 + ((((ml >> 3) ^ (dl & 7)) << 3) | (ml & 7))] = pk;
            }
        }
        __syncthreads();
        __bf16* C = qkv + 2 * 8388608;
        const int bidx = m0 >> 10, mbase = m0 & 1023;
        #pragma unroll
        for (int i = 0; i < 4; i++) {
            const int c  = tid + i * 256;        // 1024 bf16x8 chunks
            const int dl = c >> 4, u = c & 15;
            *(bf16x8*)&C[(size_t)bidx * 262144 + (size_t)(n0 + dl) * 1024 + mbase + u * 8] =
                *(const bf16x8*)&smem[dl * 128 + ((u ^ (dl & 7)) << 3)];
        }
    }
}

// ---------------------------------------------------------------------------
// logits: E[b] = exp(q[b] @ k[b]^T). R9-verified counted-vmcnt pipeline,
// 128x64 tiles, 72KB, vmcnt(6). Unchanged (byte-identical to R9).
__global__ __launch_bounds__(256)
void gemm_logits(const __bf16* __restrict__ Q, const __bf16* __restrict__ Km,
                 __bf16* __restrict__ E)
{
    __shared__ __align__(16) __bf16 smem[3 * 12288];   // 73728 B

    const int tid  = threadIdx.x;
    const int w    = tid >> 6;
    const int lane = tid & 63;
    const int quad = lane >> 4;
    const int l16  = lane & 15;
    const int wm   = w & 1;
    const int wn   = w >> 1;

    const int id = blockIdx.x;
    const int x  = id & 7, s = id >> 3;        // s: 0..511
    const int z  = x + ((s >> 7) << 3);
    const int t_ = s & 127;
    const int m0 = (t_ & 7) * 128;
    const int n0 = (t_ >> 3) * 64;

    const __bf16* Ab = Q  + (size_t)z * 262144;
    const __bf16* Bb = Km + (size_t)z * 262144;

    const int srow = (w << 3) + (lane >> 3);
    const int scol = ((lane & 7) ^ (lane >> 3)) << 3;

    const __bf16* Ag = Ab + (size_t)(m0 + srow) * 256 + scol;
    const __bf16* Bg = Bb + (size_t)(n0 + srow) * 256 + scol;

    f32x4 acc[4][2] = {};

    auto STAGE = [&](int buf, int k0) {
        char* base = (char*)smem + buf * 24576;
        #pragma unroll
        for (int c = 0; c < 4; c++)
            g2l16(Ag + (size_t)(c * 32) * 256 + k0, base + w * 1024 + c * 4096);
        #pragma unroll
        for (int c = 0; c < 2; c++)
            g2l16(Bg + (size_t)(c * 32) * 256 + k0, base + 16384 + w * 1024 + c * 4096);
    };

    STAGE(0, 0);
    STAGE(1, 64);

    for (int t = 0; t < 4; t++) {
        if (t < 3) asm volatile("s_waitcnt vmcnt(6)" ::: "memory");
        else       asm volatile("s_waitcnt vmcnt(0)" ::: "memory");
        __builtin_amdgcn_sched_barrier(0);
        __builtin_amdgcn_s_barrier();

        if (t < 2) STAGE((t + 2) % 3, (t + 2) * BK);

        const __bf16* As = smem + (t % 3) * 12288;
        const __bf16* Bs = As + 8192;
        #pragma unroll
        for (int kk = 0; kk < BK; kk += 32) {
            const int ub = kk >> 3;
            bf16x8 a[4], b[2];
            #pragma unroll
            for (int mt = 0; mt < 4; mt++) {
                const int row = wm * 64 + mt * 16 + l16;
                const int cp  = ((quad + ub) ^ (row & 7)) << 3;
                a[mt] = *(const bf16x8*)&As[row * BK + cp];
            }
            #pragma unroll
            for (int nt = 0; nt < 2; nt++) {
                const int row = wn * 32 + nt * 16 + l16;
                const int cp  = ((quad + ub) ^ (row & 7)) << 3;
                b[nt] = *(const bf16x8*)&Bs[row * BK + cp];
            }
            #pragma unroll
            for (int mt = 0; mt < 4; mt++)
                #pragma unroll
                for (int nt = 0; nt < 2; nt++)
                    acc[mt][nt] = __builtin_amdgcn_mfma_f32_16x16x32_bf16(
                        a[mt], b[nt], acc[mt][nt], 0, 0, 0);
        }
    }

    __syncthreads();
    #pragma unroll
    for (int mt = 0; mt < 4; mt++) {
        const int rl = wm * 64 + mt * 16 + quad * 4;
        #pragma unroll
        for (int nt = 0; nt < 2; nt++) {
            const int cl = wn * 32 + nt * 16 + l16;
            #pragma unroll
            for (int r = 0; r < 4; r++) {
                const int row = rl + r;
                smem[row * 64 + ((((cl >> 3) ^ (row & 7)) << 3) | (cl & 7))] =
                    (__bf16)__expf(acc[mt][nt][r]);
            }
        }
    }
    __syncthreads();
    __bf16* C = E + (size_t)z * 1048576;
    #pragma unroll
    for (int i = 0; i < 4; i++) {
        const int c   = tid + i * 256;
        const int row = c >> 3, u = c & 7;
        *(bf16x8*)&C[(size_t)(m0 + row) * 1024 + n0 + u * 8] =
            *(const bf16x8*)&smem[row * 64 + ((u ^ (row & 7)) << 3)];
    }
}

// ---------------------------------------------------------------------------
// sum_rcp: rcpS[n,m] = 1 / sum_b E[b,n,m], bf16 out (2 MB). Read-only over E.
__global__ __launch_bounds__(256)
void sum_rcp(const __bf16* __restrict__ E, __bf16* __restrict__ rcpS)
{
    const size_t p = (size_t)blockIdx.x * 256 + threadIdx.x;
    const bf16x8* E8 = (const bf16x8*)E;
    float s[8] = {0.f, 0.f, 0.f, 0.f, 0.f, 0.f, 0.f, 0.f};
    #pragma unroll
    for (int b = 0; b < 32; b++) {
        const bf16x8 e = E8[(size_t)b * 131072 + p];
        #pragma unroll
        for (int j = 0; j < 8; j++) s[j] += (float)e[j];
    }
    bf16x8 o;
    #pragma unroll
    for (int j = 0; j < 8; j++) o[j] = (__bf16)__builtin_amdgcn_rcpf(s[j]);
    ((bf16x8*)rcpS)[p] = o;
}

// ---------------------------------------------------------------------------
// pv: out[z] = (E[z] .* rcpS) @ vT[z]^T. R9-verified counted-vmcnt 3-buffer
// pipeline + fused reg-staged normalize. Unchanged (byte-identical to R9).
__global__ __launch_bounds__(256)
void gemm_pv(const __bf16* __restrict__ En, const __bf16* __restrict__ rcpS,
             const __bf16* __restrict__ vT, float* __restrict__ out)
{
    __shared__ __align__(16) __bf16 smem[3 * 12288];   // 73728 B

    const int tid  = threadIdx.x;
    const int w    = tid >> 6;
    const int lane = tid & 63;
    const int quad = lane >> 4;
    const int l16  = lane & 15;
    const int wm   = w & 1;
    const int wn   = w >> 1;

    const int id = blockIdx.x;
    const int x  = id & 7, s = id >> 3;        // s: 0..127
    const int z  = x + ((s >> 5) << 3);
    const int t_ = s & 31;
    const int m0 = (t_ & 7) * 128;
    const int n0 = (t_ >> 3) * 64;

    const __bf16* Eb = En + (size_t)z * 1048576;
    const __bf16* Vb = vT + (size_t)z * 262144;
    float*        Ob = out + (size_t)z * 262144;

    const int srow = (w << 3) + (lane >> 3);
    const int scol = ((lane & 7) ^ (lane >> 3)) << 3;

    const __bf16* Ag = Eb   + (size_t)(m0 + srow) * 1024 + scol;
    const __bf16* Rg = rcpS + (size_t)(m0 + srow) * 1024 + scol;
    const __bf16* Bg = Vb   + (size_t)(n0 + srow) * 1024 + scol;

    f32x4 acc[4][2] = {};
    bf16x8 e[4], rs[4];

    auto LOAD_ER = [&](int k0) {
        #pragma unroll
        for (int c = 0; c < 4; c++) {
            e[c]  = *(const bf16x8*)(Ag + (size_t)(c * 32) * 1024 + k0);
            rs[c] = *(const bf16x8*)(Rg + (size_t)(c * 32) * 1024 + k0);
        }
    };
    auto G2L_B = [&](int buf, int k0) {
        char* base = (char*)smem + buf * 24576 + 16384;
        #pragma unroll
        for (int c = 0; c < 2; c++)
            g2l16(Bg + (size_t)(c * 32) * 1024 + k0, base + w * 1024 + c * 4096);
    };
    auto WRITE_A = [&](int buf) {
        char* base = (char*)smem + buf * 24576;
        #pragma unroll
        for (int c = 0; c < 4; c++) {
            bf16x8 o;
            #pragma unroll
            for (int j = 0; j < 8; j++)
                o[j] = (__bf16)((float)e[c][j] * (float)rs[c][j]);
            *(bf16x8*)(base + w * 1024 + lane * 16 + c * 4096) = o;
        }
    };

    LOAD_ER(0);
    G2L_B(0, 0);
    asm volatile("s_waitcnt vmcnt(2)" ::: "memory");
    __builtin_amdgcn_sched_barrier(0);
    WRITE_A(0);
    LOAD_ER(64);
    G2L_B(1, 64);

    for (int t = 0; t < 16; t++) {
        if (t < 15) asm volatile("s_waitcnt vmcnt(2)" ::: "memory");
        else        asm volatile("s_waitcnt vmcnt(0)" ::: "memory");
        __builtin_amdgcn_sched_barrier(0);
        if (t < 15) WRITE_A((t + 1) % 3);
        asm volatile("s_waitcnt lgkmcnt(0)" ::: "memory");
        __builtin_amdgcn_sched_barrier(0);
        __builtin_amdgcn_s_barrier();

        if (t < 14) {
            LOAD_ER((t + 2) * BK);
            G2L_B((t + 2) % 3, (t + 2) * BK);
        }

        const __bf16* As = smem + (t % 3) * 12288;
        const __bf16* Bs = As + 8192;
        #pragma unroll
        for (int kk = 0; kk < BK; kk += 32) {
            const int ub = kk >> 3;
            bf16x8 a[4], b[2];
            #pragma unroll
            for (int mt = 0; mt < 4; mt++) {
                const int row = wm * 64 + mt * 16 + l16;
                const int cp  = ((quad + ub) ^ (row & 7)) << 3;
                a[mt] = *(const bf16x8*)&As[row * BK + cp];
            }
            #pragma unroll
            for (int nt = 0; nt < 2; nt++) {
                const int row = wn * 32 + nt * 16 + l16;
                const int cp  = ((quad + ub) ^ (row & 7)) << 3;
                b[nt] = *(const bf16x8*)&Bs[row * BK + cp];
            }
            #pragma unroll
            for (int mt = 0; mt < 4; mt++)
                #pragma unroll
                for (int nt = 0; nt < 2; nt++)
                    acc[mt][nt] = __builtin_amdgcn_mfma_f32_16x16x32_bf16(
                        a[mt], b[nt], acc[mt][nt], 0, 0, 0);
        }
    }

    #pragma unroll
    for (int mt = 0; mt < 4; mt++) {
        const int mb = m0 + wm * 64 + mt * 16 + quad * 4;
        #pragma unroll
        for (int nt = 0; nt < 2; nt++) {
            const int n = n0 + wn * 32 + nt * 16 + l16;
            #pragma unroll
            for (int r = 0; r < 4; r++)
                Ob[(size_t)(mb + r) * 256 + n] = acc[mt][nt][r];
        }
    }
}

// ---------------------------------------------------------------------------
// One launch: x -> bf16, Wq/Wk/Wv -> bf16, pack 3 fp32 biases.
__global__ __launch_bounds__(256)
void cvt_all(const float* __restrict__ x,
             const float* __restrict__ Wq, const float* __restrict__ Wk,
             const float* __restrict__ Wv,
             const float* __restrict__ bq, const float* __restrict__ bk,
             const float* __restrict__ bv,
             __bf16* __restrict__ xb, __bf16* __restrict__ Wqb,
             float* __restrict__ bpack)
{
    const int i = blockIdx.x * 256 + threadIdx.x;
    if (i < 1073152) {
        const float* s; __bf16* d; int off;
        if (i < 1048576)      { s = x;  d = xb;            off = i; }
        else if (i < 1056768) { s = Wq; d = Wqb;           off = i - 1048576; }
        else if (i < 1064960) { s = Wk; d = Wqb + 131072;  off = i - 1056768; }
        else                  { s = Wv; d = Wqb + 262144;  off = i - 1064960; }
        const float4* s4 = (const float4*)s;
        const float4 f0 = s4[off * 2], f1 = s4[off * 2 + 1];
        bf16x8 o;
        o[0] = (__bf16)f0.x; o[1] = (__bf16)f0.y; o[2] = (__bf16)f0.z; o[3] = (__bf16)f0.w;
        o[4] = (__bf16)f1.x; o[5] = (__bf16)f1.y; o[6] = (__bf16)f1.z; o[7] = (__bf16)f1.w;
        ((bf16x8*)d)[off] = o;
    } else if (i < 1073344) {
        const int j = i - 1073152;
        const int sel = j >> 6, jj = j & 63;
        const float* s = sel == 0 ? bq : (sel == 1 ? bk : bv);
        ((float4*)bpack)[j] = ((const float4*)s)[jj];
    }
}

extern "C" void kernel_launch(void* const* d_in, const int* in_sizes, int n_in,
                              void* d_out, int out_size, void* d_ws, size_t ws_size,
                              hipStream_t stream)
{
    const float* x  = (const float*)d_in[0];
    const float* Wq = (const float*)d_in[1];
    const float* bq = (const float*)d_in[2];
    const float* Wk = (const float*)d_in[3];
    const float* bk = (const float*)d_in[4];
    const float* Wv = (const float*)d_in[5];
    const float* bv = (const float*)d_in[6];
    float* out = (float*)d_out;

    // Workspace layout (bytes):
    //   [0,2M)     rcpS bf16 (1024x1024)
    //   [2M,18M)   xb  bf16 (32768x256)
    //   [18M,34M)  q   bf16 \
    //   [34M,50M)  k   bf16  } stride 8388608 elems
    //   [50M,66M)  vT  bf16 (32,256,1024) /
    //   [66M,130M) E   bf16 (32,1024,1024), read-only after logits
    //   [130M,..)  Wqb bf16 (3 x 65536 elems at 131072-elem stride) + bpack
    char* ws = (char*)d_ws;
    __bf16* rcpS = (__bf16*)ws;
    __bf16* xb   = (__bf16*)(ws + (2u  << 20));
    __bf16* qkv  = (__bf16*)(ws + (18u << 20));
    __bf16* E    = (__bf16*)(ws + (66u << 20));
    __bf16* Wqb  = (__bf16*)(ws + (130u << 20));
    float*  bpack = (float*)(ws + (130u << 20) + (1u << 20));

    // 1) converts + bias pack
    cvt_all<<<4194, 256, 0, stream>>>(x, Wq, Wk, Wv, bq, bk, bv, xb, Wqb, bpack);

    // 2) q/k/v projections, counted-vmcnt pipeline, 128x64 tiles
    gemm_proj<<<dim3(256, 4, 3), 256, 0, stream>>>(xb, Wqb, qkv, bpack);

    // 3) E[b] = exp(q[b] @ k[b]^T), counted-vmcnt pipeline, 128x64 tiles
    gemm_logits<<<4096, 256, 0, stream>>>(qkv, qkv + 8388608, E);

    // 4) rcpS[n,m] = 1/sum_b E[b,n,m] (read-only; no E write-back)
    sum_rcp<<<512, 256, 0, stream>>>(E, rcpS);

    // 5) out[b] = (E[b].*rcpS) @ vT[b]^T, pipelined + fused normalize
    gemm_pv<<<1024, 256, 0, stream>>>(E, rcpS, qkv + 2 * 8388608, out);
}

// Round 12
// 186.857 us; speedup vs baseline: 1.0763x; 1.0763x over previous
//
#include <hip/hip_runtime.h>

typedef __bf16 bf16x8 __attribute__((ext_vector_type(8)));
typedef __bf16 bf16x4 __attribute__((ext_vector_type(4)));
typedef float  f32x4  __attribute__((ext_vector_type(4)));

#define BK 64

__device__ __forceinline__ void g2l16(const void* g, void* l) {
    __builtin_amdgcn_global_load_lds((const __attribute__((address_space(1))) void*)g,
                                     (__attribute__((address_space(3))) void*)l, 16, 0, 0);
}

// Staging geometry (all gemms): [rows][BK=64] bf16 tiles in LDS, unpadded,
// 16B-unit XOR swizzle (unit ^= row&7) realized by swizzling the global
// SOURCE column (g2l writes lane-linear; reg-staged writes lane-linear).
// Fragment read XORs back -> 0 bank conflicts (R3-verified).

// ---------------------------------------------------------------------------
// proj: q/k/v = xb @ Wb^T + b. R10-verified counted-vmcnt pipeline
// (128x64 tile, 24KB x 3 stages, vmcnt(6), K=256 -> 4 iters). Unchanged.
__global__ __launch_bounds__(256)
void gemm_proj(const __bf16* __restrict__ A, const __bf16* __restrict__ Wb,
               __bf16* __restrict__ qkv, const float* __restrict__ bpack)
{
    __shared__ __align__(16) __bf16 smem[3 * 12288];   // 73728 B

    const int tid  = threadIdx.x;
    const int w    = tid >> 6;
    const int lane = tid & 63;
    const int quad = lane >> 4;
    const int l16  = lane & 15;
    const int wm   = w & 1;
    const int wn   = w >> 1;

    const int m0 = blockIdx.x * 128;
    const int n0 = blockIdx.y * 64;
    const int z  = blockIdx.z;

    const __bf16* Bb   = Wb + (size_t)z * 131072;
    const float*  bias = bpack + z * 256;

    const int srow = (w << 3) + (lane >> 3);
    const int scol = ((lane & 7) ^ (lane >> 3)) << 3;

    const __bf16* Ag = A  + (size_t)(m0 + srow) * 256 + scol;
    const __bf16* Bg = Bb + (size_t)(n0 + srow) * 256 + scol;

    f32x4 acc[4][2] = {};

    auto STAGE = [&](int buf, int k0) {
        char* base = (char*)smem + buf * 24576;
        #pragma unroll
        for (int c = 0; c < 4; c++)
            g2l16(Ag + (size_t)(c * 32) * 256 + k0, base + w * 1024 + c * 4096);
        #pragma unroll
        for (int c = 0; c < 2; c++)
            g2l16(Bg + (size_t)(c * 32) * 256 + k0, base + 16384 + w * 1024 + c * 4096);
    };

    STAGE(0, 0);
    STAGE(1, 64);

    for (int t = 0; t < 4; t++) {
        if (t < 3) asm volatile("s_waitcnt vmcnt(6)" ::: "memory");
        else       asm volatile("s_waitcnt vmcnt(0)" ::: "memory");
        __builtin_amdgcn_sched_barrier(0);
        __builtin_amdgcn_s_barrier();

        if (t < 2) STAGE((t + 2) % 3, (t + 2) * BK);

        const __bf16* As = smem + (t % 3) * 12288;
        const __bf16* Bs = As + 8192;
        #pragma unroll
        for (int kk = 0; kk < BK; kk += 32) {
            const int ub = kk >> 3;
            bf16x8 a[4], b[2];
            #pragma unroll
            for (int mt = 0; mt < 4; mt++) {
                const int row = wm * 64 + mt * 16 + l16;
                const int cp  = ((quad + ub) ^ (row & 7)) << 3;
                a[mt] = *(const bf16x8*)&As[row * BK + cp];
            }
            #pragma unroll
            for (int nt = 0; nt < 2; nt++) {
                const int row = wn * 32 + nt * 16 + l16;
                const int cp  = ((quad + ub) ^ (row & 7)) << 3;
                b[nt] = *(const bf16x8*)&Bs[row * BK + cp];
            }
            #pragma unroll
            for (int mt = 0; mt < 4; mt++)
                #pragma unroll
                for (int nt = 0; nt < 2; nt++)
                    acc[mt][nt] = __builtin_amdgcn_mfma_f32_16x16x32_bf16(
                        a[mt], b[nt], acc[mt][nt], 0, 0, 0);
        }
    }

    __syncthreads();
    if (z < 2) {
        #pragma unroll
        for (int mt = 0; mt < 4; mt++) {
            const int rl = wm * 64 + mt * 16 + quad * 4;
            #pragma unroll
            for (int nt = 0; nt < 2; nt++) {
                const int cl = wn * 32 + nt * 16 + l16;
                const float bn = bias[n0 + cl];
                #pragma unroll
                for (int r = 0; r < 4; r++) {
                    const int row = rl + r;
                    smem[row * 64 + ((((cl >> 3) ^ (row & 7)) << 3) | (cl & 7))] =
                        (__bf16)(acc[mt][nt][r] + bn);
                }
            }
        }
        __syncthreads();
        __bf16* C = qkv + (size_t)z * 8388608;
        #pragma unroll
        for (int i = 0; i < 4; i++) {
            const int c   = tid + i * 256;
            const int row = c >> 3, u = c & 7;
            *(bf16x8*)&C[(size_t)(m0 + row) * 256 + n0 + u * 8] =
                *(const bf16x8*)&smem[row * 64 + ((u ^ (row & 7)) << 3)];
        }
    } else {
        #pragma unroll
        for (int mt = 0; mt < 4; mt++) {
            const int ml = wm * 64 + mt * 16 + quad * 4;
            #pragma unroll
            for (int nt = 0; nt < 2; nt++) {
                const int dl = wn * 32 + nt * 16 + l16;
                const float bn = bias[n0 + dl];
                bf16x4 pk;
                #pragma unroll
                for (int r = 0; r < 4; r++) pk[r] = (__bf16)(acc[mt][nt][r] + bn);
                *(bf16x4*)&smem[dl * 128 + ((((ml >> 3) ^ (dl & 7)) << 3) | (ml & 7))] = pk;
            }
        }
        __syncthreads();
        __bf16* C = qkv + 2 * 8388608;
        const int bidx = m0 >> 10, mbase = m0 & 1023;
        #pragma unroll
        for (int i = 0; i < 4; i++) {
            const int c  = tid + i * 256;
            const int dl = c >> 4, u = c & 15;
            *(bf16x8*)&C[(size_t)bidx * 262144 + (size_t)(n0 + dl) * 1024 + mbase + u * 8] =
                *(const bf16x8*)&smem[dl * 128 + ((u ^ (dl & 7)) << 3)];
        }
    }
}

// ---------------------------------------------------------------------------
// logits: E[b] = exp(q[b] @ k[b]^T). R9-verified counted-vmcnt pipeline.
// Unchanged (byte-identical to R9/R10).
__global__ __launch_bounds__(256)
void gemm_logits(const __bf16* __restrict__ Q, const __bf16* __restrict__ Km,
                 __bf16* __restrict__ E)
{
    __shared__ __align__(16) __bf16 smem[3 * 12288];   // 73728 B

    const int tid  = threadIdx.x;
    const int w    = tid >> 6;
    const int lane = tid & 63;
    const int quad = lane >> 4;
    const int l16  = lane & 15;
    const int wm   = w & 1;
    const int wn   = w >> 1;

    const int id = blockIdx.x;
    const int x  = id & 7, s = id >> 3;        // s: 0..511
    const int z  = x + ((s >> 7) << 3);
    const int t_ = s & 127;
    const int m0 = (t_ & 7) * 128;
    const int n0 = (t_ >> 3) * 64;

    const __bf16* Ab = Q  + (size_t)z * 262144;
    const __bf16* Bb = Km + (size_t)z * 262144;

    const int srow = (w << 3) + (lane >> 3);
    const int scol = ((lane & 7) ^ (lane >> 3)) << 3;

    const __bf16* Ag = Ab + (size_t)(m0 + srow) * 256 + scol;
    const __bf16* Bg = Bb + (size_t)(n0 + srow) * 256 + scol;

    f32x4 acc[4][2] = {};

    auto STAGE = [&](int buf, int k0) {
        char* base = (char*)smem + buf * 24576;
        #pragma unroll
        for (int c = 0; c < 4; c++)
            g2l16(Ag + (size_t)(c * 32) * 256 + k0, base + w * 1024 + c * 4096);
        #pragma unroll
        for (int c = 0; c < 2; c++)
            g2l16(Bg + (size_t)(c * 32) * 256 + k0, base + 16384 + w * 1024 + c * 4096);
    };

    STAGE(0, 0);
    STAGE(1, 64);

    for (int t = 0; t < 4; t++) {
        if (t < 3) asm volatile("s_waitcnt vmcnt(6)" ::: "memory");
        else       asm volatile("s_waitcnt vmcnt(0)" ::: "memory");
        __builtin_amdgcn_sched_barrier(0);
        __builtin_amdgcn_s_barrier();

        if (t < 2) STAGE((t + 2) % 3, (t + 2) * BK);

        const __bf16* As = smem + (t % 3) * 12288;
        const __bf16* Bs = As + 8192;
        #pragma unroll
        for (int kk = 0; kk < BK; kk += 32) {
            const int ub = kk >> 3;
            bf16x8 a[4], b[2];
            #pragma unroll
            for (int mt = 0; mt < 4; mt++) {
                const int row = wm * 64 + mt * 16 + l16;
                const int cp  = ((quad + ub) ^ (row & 7)) << 3;
                a[mt] = *(const bf16x8*)&As[row * BK + cp];
            }
            #pragma unroll
            for (int nt = 0; nt < 2; nt++) {
                const int row = wn * 32 + nt * 16 + l16;
                const int cp  = ((quad + ub) ^ (row & 7)) << 3;
                b[nt] = *(const bf16x8*)&Bs[row * BK + cp];
            }
            #pragma unroll
            for (int mt = 0; mt < 4; mt++)
                #pragma unroll
                for (int nt = 0; nt < 2; nt++)
                    acc[mt][nt] = __builtin_amdgcn_mfma_f32_16x16x32_bf16(
                        a[mt], b[nt], acc[mt][nt], 0, 0, 0);
        }
    }

    __syncthreads();
    #pragma unroll
    for (int mt = 0; mt < 4; mt++) {
        const int rl = wm * 64 + mt * 16 + quad * 4;
        #pragma unroll
        for (int nt = 0; nt < 2; nt++) {
            const int cl = wn * 32 + nt * 16 + l16;
            #pragma unroll
            for (int r = 0; r < 4; r++) {
                const int row = rl + r;
                smem[row * 64 + ((((cl >> 3) ^ (row & 7)) << 3) | (cl & 7))] =
                    (__bf16)__expf(acc[mt][nt][r]);
            }
        }
    }
    __syncthreads();
    __bf16* C = E + (size_t)z * 1048576;
    #pragma unroll
    for (int i = 0; i < 4; i++) {
        const int c   = tid + i * 256;
        const int row = c >> 3, u = c & 7;
        *(bf16x8*)&C[(size_t)(m0 + row) * 1024 + n0 + u * 8] =
            *(const bf16x8*)&smem[row * 64 + ((u ^ (row & 7)) << 3)];
    }
}

// ---------------------------------------------------------------------------
// sum_rcp: rcpS[n,m] = 1 / sum_b E[b,n,m], bf16 out (2 MB). Read-only over E.
__global__ __launch_bounds__(256)
void sum_rcp(const __bf16* __restrict__ E, __bf16* __restrict__ rcpS)
{
    const size_t p = (size_t)blockIdx.x * 256 + threadIdx.x;
    const bf16x8* E8 = (const bf16x8*)E;
    float s[8] = {0.f, 0.f, 0.f, 0.f, 0.f, 0.f, 0.f, 0.f};
    #pragma unroll
    for (int b = 0; b < 32; b++) {
        const bf16x8 e = E8[(size_t)b * 131072 + p];
        #pragma unroll
        for (int j = 0; j < 8; j++) s[j] += (float)e[j];
    }
    bf16x8 o;
    #pragma unroll
    for (int j = 0; j < 8; j++) o[j] = (__bf16)__builtin_amdgcn_rcpf(s[j]);
    ((bf16x8*)rcpS)[p] = o;
}

// ---------------------------------------------------------------------------
// pv: out[z] = (E[z] .* rcpS) @ vT[z]^T. R11/R12: 128x256 tile (FULL d-width).
// R10 diagnosis: 128x64 tiles re-read each E-slice 4x and rcpS 128x ->
// ~770MB logical L2/L3 traffic ~= the measured 48us across 4 schedules.
// Big tile cuts logical traffic ~3x (E read ONCE). Grid 256 = 1 block/CU;
// 2-stage x 48KB = 96KB LDS (m201 precedent: 128KB static OK), depth-1
// counted pipeline, fused normalize (reg-staged A). Stage = 8 ER reg-loads
// + 8 B-g2l = 16 VMEM. Ledger (t=0/steady/14/15 verified): top-of-iter
// vmcnt(16) certifies B_t; tail vmcnt(8) certifies ER_{t+1}; WRITE_A's
// target was last read two barriers back. z-per-XCD swizzle.
__global__ __launch_bounds__(256, 1)
void gemm_pv(const __bf16* __restrict__ En, const __bf16* __restrict__ rcpS,
             const __bf16* __restrict__ vT, float* __restrict__ out)
{
    __shared__ __align__(16) __bf16 smem[2 * 24576];   // 98304 B
    // stage s at byte s*49152: A [128][64] (16KB), B [256][64] at +16384 (32KB)

    const int tid  = threadIdx.x;
    const int w    = tid >> 6;
    const int lane = tid & 63;
    const int quad = lane >> 4;
    const int l16  = lane & 15;
    const int wm   = w & 1;        // 64-row half (n)
    const int wn   = w >> 1;       // 128-col half (d)

    const int id = blockIdx.x;                 // 0..255
    const int x  = id & 7, g = id >> 3;        // x: XCD slot
    const int z  = x + ((g & 3) << 3);         // 4 batches per XCD
    const int m0 = (g >> 2) * 128;             // 8 m-tiles

    const __bf16* Eb = En + (size_t)z * 1048576;
    const __bf16* Vb = vT + (size_t)z * 262144;
    float*        Ob = out + (size_t)z * 262144;

    const int srow = (w << 3) + (lane >> 3);   // 0..31
    const int scol = ((lane & 7) ^ (lane >> 3)) << 3;

    const __bf16* Ag = Eb   + (size_t)(m0 + srow) * 1024 + scol;
    const __bf16* Rg = rcpS + (size_t)(m0 + srow) * 1024 + scol;
    const __bf16* Bg = Vb   + (size_t)srow * 1024 + scol;   // d rows 0..255

    f32x4 acc[4][8] = {};
    bf16x8 e[4], rs[4];

    auto LOAD_ER = [&](int k0) {               // 8 VMEM
        #pragma unroll
        for (int c = 0; c < 4; c++) {
            e[c]  = *(const bf16x8*)(Ag + (size_t)(c * 32) * 1024 + k0);
            rs[c] = *(const bf16x8*)(Rg + (size_t)(c * 32) * 1024 + k0);
        }
    };
    auto G2L_B = [&](int buf, int k0) {        // 8 VMEM (256 d-rows)
        char* base = (char*)smem + buf * 49152 + 16384;
        #pragma unroll
        for (int c = 0; c < 8; c++)
            g2l16(Bg + (size_t)(c * 32) * 1024 + k0, base + w * 1024 + c * 4096);
    };
    auto WRITE_A = [&](int buf) {              // 4 ds_write_b128
        char* base = (char*)smem + buf * 49152;
        #pragma unroll
        for (int c = 0; c < 4; c++) {
            bf16x8 o;
            #pragma unroll
            for (int j = 0; j < 8; j++)
                o[j] = (__bf16)((float)e[c][j] * (float)rs[c][j]);
            *(bf16x8*)(base + w * 1024 + lane * 16 + c * 4096) = o;
        }
    };

    // prologue
    LOAD_ER(0);
    G2L_B(0, 0);                                       // out: 16
    asm volatile("s_waitcnt vmcnt(8)" ::: "memory");   // ER_0 landed
    __builtin_amdgcn_sched_barrier(0);
    WRITE_A(0);
    LOAD_ER(64);
    G2L_B(1, 64);                                      // out: B0(8)+S1(16)=24

    for (int t = 0; t < 16; t++) {
        if (t < 15) asm volatile("s_waitcnt vmcnt(16)" ::: "memory");  // B_t
        else        asm volatile("s_waitcnt vmcnt(0)"  ::: "memory");
        __builtin_amdgcn_sched_barrier(0);
        asm volatile("s_waitcnt lgkmcnt(0)" ::: "memory");  // A_t writes visible
        __builtin_amdgcn_sched_barrier(0);
        __builtin_amdgcn_s_barrier();                       // #1: buf t ready

        const __bf16* As = smem + (t & 1) * 24576;
        const __bf16* Bs = As + 8192;
        #pragma unroll
        for (int kk = 0; kk < BK; kk += 32) {
            const int ub = kk >> 3;
            bf16x8 a[4], b[8];
            #pragma unroll
            for (int mt = 0; mt < 4; mt++) {
                const int row = wm * 64 + mt * 16 + l16;
                const int cp  = ((quad + ub) ^ (row & 7)) << 3;
                a[mt] = *(const bf16x8*)&As[row * BK + cp];
            }
            #pragma unroll
            for (int nt = 0; nt < 8; nt++) {
                const int row = wn * 128 + nt * 16 + l16;
                const int cp  = ((quad + ub) ^ (row & 7)) << 3;
                b[nt] = *(const bf16x8*)&Bs[row * BK + cp];
            }
            #pragma unroll
            for (int mt = 0; mt < 4; mt++)
                #pragma unroll
                for (int nt = 0; nt < 8; nt++)
                    acc[mt][nt] = __builtin_amdgcn_mfma_f32_16x16x32_bf16(
                        a[mt], b[nt], acc[mt][nt], 0, 0, 0);
        }

        __builtin_amdgcn_s_barrier();                       // #2: buf t free

        if (t < 15) {
            asm volatile("s_waitcnt vmcnt(8)" ::: "memory");  // ER_{t+1} landed
            __builtin_amdgcn_sched_barrier(0);
            WRITE_A((t + 1) & 1);
            if (t < 14) {
                LOAD_ER((t + 2) * BK);
                G2L_B(t & 1, (t + 2) * BK);
            }
        }
    }

    // fp32 direct stores: 16 lanes x 4B = full 64B lines.
    #pragma unroll
    for (int mt = 0; mt < 4; mt++) {
        const int mb = m0 + wm * 64 + mt * 16 + quad * 4;
        #pragma unroll
        for (int nt = 0; nt < 8; nt++) {
            const int n = wn * 128 + nt * 16 + l16;
            #pragma unroll
            for (int r = 0; r < 4; r++)
                Ob[(size_t)(mb + r) * 256 + n] = acc[mt][nt][r];
        }
    }
}

// ---------------------------------------------------------------------------
// One launch: x -> bf16, Wq/Wk/Wv -> bf16, pack 3 fp32 biases.
__global__ __launch_bounds__(256)
void cvt_all(const float* __restrict__ x,
             const float* __restrict__ Wq, const float* __restrict__ Wk,
             const float* __restrict__ Wv,
             const float* __restrict__ bq, const float* __restrict__ bk,
             const float* __restrict__ bv,
             __bf16* __restrict__ xb, __bf16* __restrict__ Wqb,
             float* __restrict__ bpack)
{
    const int i = blockIdx.x * 256 + threadIdx.x;
    if (i < 1073152) {
        const float* s; __bf16* d; int off;
        if (i < 1048576)      { s = x;  d = xb;            off = i; }
        else if (i < 1056768) { s = Wq; d = Wqb;           off = i - 1048576; }
        else if (i < 1064960) { s = Wk; d = Wqb + 131072;  off = i - 1056768; }
        else                  { s = Wv; d = Wqb + 262144;  off = i - 1064960; }
        const float4* s4 = (const float4*)s;
        const float4 f0 = s4[off * 2], f1 = s4[off * 2 + 1];
        bf16x8 o;
        o[0] = (__bf16)f0.x; o[1] = (__bf16)f0.y; o[2] = (__bf16)f0.z; o[3] = (__bf16)f0.w;
        o[4] = (__bf16)f1.x; o[5] = (__bf16)f1.y; o[6] = (__bf16)f1.z; o[7] = (__bf16)f1.w;
        ((bf16x8*)d)[off] = o;
    } else if (i < 1073344) {
        const int j = i - 1073152;
        const int sel = j >> 6, jj = j & 63;
        const float* s = sel == 0 ? bq : (sel == 1 ? bk : bv);
        ((float4*)bpack)[j] = ((const float4*)s)[jj];
    }
}

extern "C" void kernel_launch(void* const* d_in, const int* in_sizes, int n_in,
                              void* d_out, int out_size, void* d_ws, size_t ws_size,
                              hipStream_t stream)
{
    const float* x  = (const float*)d_in[0];
    const float* Wq = (const float*)d_in[1];
    const float* bq = (const float*)d_in[2];
    const float* Wk = (const float*)d_in[3];
    const float* bk = (const float*)d_in[4];
    const float* Wv = (const float*)d_in[5];
    const float* bv = (const float*)d_in[6];
    float* out = (float*)d_out;

    // Workspace layout (bytes):
    //   [0,2M)     rcpS bf16 (1024x1024)
    //   [2M,18M)   xb  bf16 (32768x256)
    //   [18M,34M)  q   bf16 \
    //   [34M,50M)  k   bf16  } stride 8388608 elems
    //   [50M,66M)  vT  bf16 (32,256,1024) /
    //   [66M,130M) E   bf16 (32,1024,1024), read-only after logits
    //   [130M,..)  Wqb bf16 (3 x 65536 elems at 131072-elem stride) + bpack
    char* ws = (char*)d_ws;
    __bf16* rcpS = (__bf16*)ws;
    __bf16* xb   = (__bf16*)(ws + (2u  << 20));
    __bf16* qkv  = (__bf16*)(ws + (18u << 20));
    __bf16* E    = (__bf16*)(ws + (66u << 20));
    __bf16* Wqb  = (__bf16*)(ws + (130u << 20));
    float*  bpack = (float*)(ws + (130u << 20) + (1u << 20));

    // 1) converts + bias pack
    cvt_all<<<4194, 256, 0, stream>>>(x, Wq, Wk, Wv, bq, bk, bv, xb, Wqb, bpack);

    // 2) q/k/v projections, counted-vmcnt pipeline, 128x64 tiles
    gemm_proj<<<dim3(256, 4, 3), 256, 0, stream>>>(xb, Wqb, qkv, bpack);

    // 3) E[b] = exp(q[b] @ k[b]^T), counted-vmcnt pipeline, 128x64 tiles
    gemm_logits<<<4096, 256, 0, stream>>>(qkv, qkv + 8388608, E);

    // 4) rcpS[n,m] = 1/sum_b E[b,n,m] (read-only; no E write-back)
    sum_rcp<<<512, 256, 0, stream>>>(E, rcpS);

    // 5) out[b] = (E[b].*rcpS) @ vT[b]^T, 128x256 big-tile, 1 block/CU
    gemm_pv<<<256, 256, 0, stream>>>(E, rcpS, qkv + 2 * 8388608, out);
}